// Round 9
// baseline (276.776 us; speedup 1.0000x reference)
//
#include <hip/hip_runtime.h>
#include <stdint.h>

typedef __attribute__((ext_vector_type(8))) short bf16x8;
typedef __attribute__((ext_vector_type(4))) float f32x4;
typedef unsigned short ushort_t;

#define AS1 __attribute__((address_space(1)))
#define AS3 __attribute__((address_space(3)))

static __device__ __forceinline__ ushort_t f2b(float f) {
    union { float f; unsigned u; } x; x.f = f;
    unsigned r = x.u + 0x7fffu + ((x.u >> 16) & 1u);  // RNE bf16
    return (ushort_t)(r >> 16);
}
static __device__ __forceinline__ f32x4 mfma16(bf16x8 a, bf16x8 b, f32x4 c) {
    return __builtin_amdgcn_mfma_f32_16x16x32_bf16(a, b, c, 0, 0, 0);
}
static __device__ __forceinline__ void gl_lds16(const ushort_t* g, ushort_t* l) {
    __builtin_amdgcn_global_load_lds((const AS1 void*)g, (AS3 void*)l, 16, 0, 0);
}
// packed fp32x2 -> bf16x2 (RNE), lo = a, hi = b
static __device__ __forceinline__ unsigned pk2(float a, float b) {
    unsigned r;
    asm("v_cvt_pk_bf16_f32 %0, %1, %2" : "=v"(r) : "v"(a), "v"(b));
    return r;
}

// fp32 -> bf16 RNE, 8 elems/thread.
__global__ __launch_bounds__(256)
void cvt_bf16(const float* __restrict__ s, ushort_t* __restrict__ d, int n8)
{
    int i = blockIdx.x * 256 + threadIdx.x;
    if (i >= n8) return;
    const float* p = s + (size_t)i * 8;
    f32x4 a = *(const f32x4*)p;
    f32x4 b = *(const f32x4*)(p + 4);
    bf16x8 r;
#pragma unroll
    for (int j = 0; j < 4; ++j) { r[j] = (short)f2b(a[j]); r[j+4] = (short)f2b(b[j]); }
    *(bf16x8*)(d + (size_t)i * 8) = r;
}

// 3 weight matrices (each 1024x2048 fp32) -> concatenated bf16 [3072][2048].
__global__ __launch_bounds__(256)
void cvt_w3(const float* __restrict__ wq, const float* __restrict__ wk,
            const float* __restrict__ wv, ushort_t* __restrict__ d)
{
    const float* s = (blockIdx.y == 0) ? wq : (blockIdx.y == 1) ? wk : wv;
    ushort_t* dst = d + (size_t)blockIdx.y * 2097152;
    int i = blockIdx.x * 256 + threadIdx.x;          // grid.x = 1024 -> i < 262144
    const float* p = s + (size_t)i * 8;
    f32x4 a = *(const f32x4*)p;
    f32x4 b = *(const f32x4*)(p + 4);
    bf16x8 r;
#pragma unroll
    for (int j = 0; j < 4; ++j) { r[j] = (short)f2b(a[j]); r[j+4] = (short)f2b(b[j]); }
    *(bf16x8*)(dst + (size_t)i * 8) = r;
}

// 128x384 8-phase NT-GEMM for the fused QKV (round-9: merged pair-reads).
// Grid (32, 8) = 256 blocks = full fill. 8 waves (2M x 4N), per-wave C =
// 64x96 (acc[4][6]). Ring: 4 slice-pairs x {B 24KB (3 ops), A 8KB (1 op)}
// = 128KB. EVEN phases read ALL 10 fragments of the slice-pair (6 B + 4 A);
// ODD phases have zero ds_reads -> no lgkmcnt stall, pure-MFMA burst that
// overlaps the other wave's read phase. vmcnt(7) at p==3/7 unchanged
// (phase-0 reads of iter t+1 need stages <= 8t+11, guaranteed at p==7).
// WAR: even phase p reads slots {p,p+1}; stages at p/p+1 write slot p-1,
// disjoint, ordered by closing barriers. st_16x32 swizzle both-sides.
// epi routing: col -> mat=col>>10 (0:Q 1:K 2:V); V TRANSPOSED [(b*32+h)][d][s].
__global__ __launch_bounds__(512, 1)
void gemm8c(const ushort_t* __restrict__ A, const ushort_t* __restrict__ B,
            const float* __restrict__ b0, const float* __restrict__ b1,
            const float* __restrict__ b2, void* __restrict__ Cv,
            int M, int N, int K)
{
    __shared__ __align__(16) ushort_t lds[65536];   // 4 x (24KB B + 8KB A) = 128KB
    const int tid = threadIdx.x;
    const int wave = tid >> 6, lane = tid & 63;
    const int l16 = lane & 15, quad = lane >> 4;
    const int wr = wave >> 2, wc = wave & 3;        // 2 x 4 wave grid
    const int bm = blockIdx.x * 128, bn = blockIdx.y * 384;
    const int xo = (l16 & 8) << 1;                  // st_16x32 read XOR (ushorts)
    const int S = K >> 4;                           // stages (2 per 32-k slice)
    const int NT = K >> 7;                          // iterations (128 K each)

    f32x4 acc[4][6];
#pragma unroll
    for (int i = 0; i < 4; ++i)
#pragma unroll
        for (int j = 0; j < 6; ++j) acc[i][j] = (f32x4){0.f,0.f,0.f,0.f};

    // stage s: slot = s&7, slice pair sp = slot>>1, base = sp*16384 ushorts;
    // even s = B k-slice s/2 (24KB, 3 ops), odd s = A k-slice (8KB, 1 op).
    auto stg = [&](int s_) {
        int slot = s_ & 7;
        ushort_t* base = lds + (slot >> 1) * 16384;
        int ko = (s_ >> 1) << 5;
        if (s_ & 1) {
            int c = tid;
            int cl = c ^ (((c >> 5) & 1) << 1);
            gl_lds16(A + (size_t)(bm + (cl >> 2)) * K + ko + (cl & 3) * 8,
                     base + 12288 + c * 8);
        } else {
#pragma unroll
            for (int call = 0; call < 3; ++call) {
                int c = call * 512 + tid;
                int cl = c ^ (((c >> 5) & 1) << 1);
                gl_lds16(B + (size_t)(bn + (cl >> 2)) * K + ko + (cl & 3) * 8,
                         base + c * 8);
            }
        }
    };

    // prologue: stages 0..6 (15 ops); vmcnt(7) -> stages 0-3 landed
#pragma unroll
    for (int s0 = 0; s0 < 7; ++s0) stg(s0);
    asm volatile("s_waitcnt vmcnt(7)" ::: "memory");
    __builtin_amdgcn_s_barrier();

    for (int t = 0; t < NT; ++t) {
        const bool lastit = (t == NT - 1);
        bf16x8 bfr[6], af[4];
#pragma unroll
        for (int p = 0; p < 8; ++p) {
            asm volatile("" ::: "memory");
            const int offB = (p >> 1) * 16384;
            const int offA = offB + 12288;
            if ((p & 1) == 0) {   // read the WHOLE slice-pair: 6 B + 4 A
#pragma unroll
                for (int j = 0; j < 6; ++j)
                    bfr[j] = *(const bf16x8*)(lds + offB
                              + (wc * 96 + j * 16 + l16) * 32 + ((quad * 8) ^ xo));
#pragma unroll
                for (int m = 0; m < 4; ++m)
                    af[m] = *(const bf16x8*)(lds + offA
                              + (wr * 64 + m * 16 + l16) * 32 + ((quad * 8) ^ xo));
            }
            { int s_ = 8 * t + 7 + p; if (s_ < S) stg(s_); }
            __builtin_amdgcn_s_barrier();
            if ((p & 1) == 0) {   // odd phases: regs already loaded, no stall
                asm volatile("s_waitcnt lgkmcnt(0)" ::: "memory");
                __builtin_amdgcn_sched_barrier(0);  // rule #18: no MFMA hoist
            }
            __builtin_amdgcn_s_setprio(1);
#pragma unroll
            for (int m = 0; m < 2; ++m)
#pragma unroll
                for (int j = 0; j < 6; ++j)
                    acc[(p & 1) * 2 + m][j] =
                        mfma16(af[(p & 1) * 2 + m], bfr[j], acc[(p & 1) * 2 + m][j]);
            __builtin_amdgcn_s_setprio(0);
            if (p == 3) {
                if (lastit) asm volatile("s_waitcnt vmcnt(0)" ::: "memory");
                else        asm volatile("s_waitcnt vmcnt(7)" ::: "memory");
            } else if (p == 7) {
                if (!lastit) asm volatile("s_waitcnt vmcnt(7)" ::: "memory");
            }
            __builtin_amdgcn_s_barrier();
        }
    }

    // epilogue: row = bm + wr*64 + i*16 + quad*4 + r, col = bn + wc*96 + j*16 + l16
#pragma unroll
    for (int i = 0; i < 4; ++i) {
#pragma unroll
        for (int j = 0; j < 6; ++j) {
            int col = bn + wc * 96 + j * 16 + l16;
            int mat = col >> 10, nc = col & 1023;   // uniform across l16 group
            const float* bp = (mat == 0) ? b0 : (mat == 1) ? b1 : b2;
            float bvs = bp[nc];
            int h = nc >> 5, d = nc & 31;
            if (mat == 2) {
                // V^T: [(b*32+h)][d][s], 4 consecutive s packed per lane
                int row0 = bm + wr * 64 + i * 16 + quad * 4;
                int b = row0 >> 11, s2 = row0 & 2047;
                ushort_t* dst = (ushort_t*)Cv + (size_t)2 * 4194304
                              + ((size_t)(b * 32 + h) * 32 + d) * 2048 + s2;
                uint2 w;
                w.x = ((unsigned)f2b(acc[i][j][1] + bvs) << 16) | f2b(acc[i][j][0] + bvs);
                w.y = ((unsigned)f2b(acc[i][j][3] + bvs) << 16) | f2b(acc[i][j][2] + bvs);
                *(uint2*)dst = w;
            } else {
                float sc = (mat == 0) ? 0.125f : 1.0f;
                ushort_t* dst = (ushort_t*)Cv + (size_t)mat * 4194304;
#pragma unroll
                for (int r = 0; r < 4; ++r) {
                    int row = bm + wr * 64 + i * 16 + quad * 4 + r;
                    int b = row >> 11, s2 = row & 2047;
                    float v = (acc[i][j][r] + bvs) * sc;
                    dst[(((size_t)(b * 32 + h) * 2048 + s2) << 5) + d] = f2b(v);
                }
            }
        }
    }
}

// 128x256 8-phase NT-GEMM for the output projection: grid (32, 8) = 256
// blocks -> FULL machine fill. 8 waves (2M x 4N), per-wave C = 64x64.
// Ring: 8 regions, even = B-slice 16KB (2 stage calls), odd = A-slice 8KB
// (1 call) -> 96KB. vmcnt(5) at p==3/7; vmcnt(0) drain at last iteration.
// st_16x32 swizzle both-sides.
__global__ __launch_bounds__(512, 1)
void gemm8b(const ushort_t* __restrict__ A, const ushort_t* __restrict__ B,
            const float* __restrict__ bias, float* __restrict__ C,
            int M, int N, int K, float scale)
{
    __shared__ __align__(16) ushort_t lds[49152];   // 96KB
    const int tid = threadIdx.x;
    const int wave = tid >> 6, lane = tid & 63;
    const int l16 = lane & 15, quad = lane >> 4;
    const int wr = wave >> 2, wc = wave & 3;        // 2 x 4 wave grid
    const int bm = blockIdx.x * 128, bn = blockIdx.y * 256;
    const int xo = (l16 & 8) << 1;                  // st_16x32 read XOR (ushorts)
    const int S = K >> 4;                           // 2 stages per 32-k slice
    const int NT = K >> 7;                          // iterations (128 K each)

    f32x4 acc[4][4];
#pragma unroll
    for (int i = 0; i < 4; ++i)
#pragma unroll
        for (int j = 0; j < 4; ++j) acc[i][j] = (f32x4){0.f,0.f,0.f,0.f};

    // stage s: region r = s&7 at ushort offset (r>>1)*12288 + (r&1)*8192;
    // even s = B k-slice s/2 (16KB, 2 calls), odd s = A k-slice (8KB, 1 call).
    auto stg = [&](int s_) {
        int r = s_ & 7;
        ushort_t* ldst = lds + (r >> 1) * 12288 + (r & 1) * 8192;
        int ko = (s_ >> 1) << 5;
        if (s_ & 1) {
            int c = tid;
            int cl = c ^ (((c >> 5) & 1) << 1);
            gl_lds16(A + (size_t)(bm + (cl >> 2)) * K + ko + (cl & 3) * 8,
                     ldst + c * 8);
        } else {
#pragma unroll
            for (int call = 0; call < 2; ++call) {
                int c = call * 512 + tid;
                int cl = c ^ (((c >> 5) & 1) << 1);
                gl_lds16(B + (size_t)(bn + (cl >> 2)) * K + ko + (cl & 3) * 8,
                         ldst + c * 8);
            }
        }
    };

    // prologue: 7 stages (11 ops); vmcnt(5) -> stages 0-3 landed (phases 0-3)
#pragma unroll
    for (int s0 = 0; s0 < 7; ++s0) stg(s0);
    asm volatile("s_waitcnt vmcnt(5)" ::: "memory");
    __builtin_amdgcn_s_barrier();

    for (int t = 0; t < NT; ++t) {
        const bool lastit = (t == NT - 1);
        bf16x8 bfr[4], af[2];
#pragma unroll
        for (int p = 0; p < 8; ++p) {
            asm volatile("" ::: "memory");
            const int offB = (p >> 1) * 12288;
            const int offA = offB + 8192;
            if ((p & 1) == 0) {                     // new k-slice: read B once
#pragma unroll
                for (int j = 0; j < 4; ++j)
                    bfr[j] = *(const bf16x8*)(lds + offB
                              + (wc * 64 + j * 16 + l16) * 32 + ((quad * 8) ^ xo));
            }
#pragma unroll
            for (int m = 0; m < 2; ++m)
                af[m] = *(const bf16x8*)(lds + offA
                          + (wr * 64 + (p & 1) * 32 + m * 16 + l16) * 32
                          + ((quad * 8) ^ xo));
            { int s_ = 8 * t + 7 + p; if (s_ < S) stg(s_); }
            __builtin_amdgcn_s_barrier();
            asm volatile("s_waitcnt lgkmcnt(0)" ::: "memory");
            __builtin_amdgcn_sched_barrier(0);      // rule #18: no MFMA hoist
            __builtin_amdgcn_s_setprio(1);
#pragma unroll
            for (int m = 0; m < 2; ++m)
#pragma unroll
                for (int j = 0; j < 4; ++j)
                    acc[(p & 1) * 2 + m][j] =
                        mfma16(af[m], bfr[j], acc[(p & 1) * 2 + m][j]);
            __builtin_amdgcn_s_setprio(0);
            if (p == 3) {
                if (lastit) asm volatile("s_waitcnt vmcnt(0)" ::: "memory");
                else        asm volatile("s_waitcnt vmcnt(5)" ::: "memory");
            } else if (p == 7) {
                if (!lastit) asm volatile("s_waitcnt vmcnt(5)" ::: "memory");
            }
            __builtin_amdgcn_s_barrier();
        }
    }

    // epilogue: row = bm + wr*64 + i*16 + quad*4 + r, col = bn + wc*64 + j*16 + l16
#pragma unroll
    for (int i = 0; i < 4; ++i) {
#pragma unroll
        for (int j = 0; j < 4; ++j) {
            int col = bn + wc * 64 + j * 16 + l16;
            float bvs = bias[col];
#pragma unroll
            for (int r = 0; r < 4; ++r) {
                int row = bm + wr * 64 + i * 16 + quad * 4 + r;
                C[(size_t)row * N + col] = (acc[i][j][r] + bvs) * scale;
            }
        }
    }
}

// Flash-style causal attention, barrier-free, CAUSAL-BALANCED: each block
// processes the strip pair (qt, 15-qt) -> constant 34 chunks/block.
// Grid (64 bh, 8 pairs), 256 threads. Swapped QK^T (mfma(K,Q)) puts q on
// l16 so P lands in the PV A-fragment layout; Ps round-trip = 8x
// ds_write_b64 (cvt_pk) + 4x ds_read_b128. K and V^T straight from global.
__global__ __launch_bounds__(256, 4)
void attn(const ushort_t* __restrict__ Q, const ushort_t* __restrict__ Kg,
          const ushort_t* __restrict__ VT, ushort_t* __restrict__ Ctx)
{
    __shared__ __align__(16) ushort_t Ps[4][32 * 72];  // per-wave, padded rows
    const int tid = threadIdx.x, wave = tid >> 6, lane = tid & 63;
    const int l16 = lane & 15, quad = lane >> 4, quad4 = quad * 4;
    const int bh = blockIdx.x;   // 0..63
    const int pr = blockIdx.y;   // 0..7 (strip pair)
    const ushort_t* Qh = Q  + (size_t)bh * 2048 * 32;
    const ushort_t* Kh = Kg + (size_t)bh * 2048 * 32;
    const ushort_t* Vh = VT + (size_t)bh * 32 * 2048;
    const int b = bh >> 5, h = bh & 31;
    ushort_t* P0 = &Ps[wave][0];

    for (int half = 0; half < 2; ++half) {
        const int qt = half ? (15 - pr) : pr;
        const int q0 = qt * 128 + wave * 32;   // wave's 32-row strip

        bf16x8 qf0 = *(const bf16x8*)(Qh + (size_t)(q0 + l16) * 32 + quad * 8);
        bf16x8 qf1 = *(const bf16x8*)(Qh + (size_t)(q0 + 16 + l16) * 32 + quad * 8);

        f32x4 o00 = (f32x4){0.f,0.f,0.f,0.f}, o01 = o00, o10 = o00, o11 = o00;
        float rs0 = 0.f, rs1 = 0.f;

        const int nchw = ((q0 + 31) >> 6) + 1;
        for (int c = 0; c < nchw; ++c) {
            const int kv0 = c * 64;
            bf16x8 kf[4];
#pragma unroll
            for (int t = 0; t < 4; ++t)
                kf[t] = *(const bf16x8*)(Kh + (size_t)(kv0 + t * 16 + l16) * 32 + quad * 8);
            f32x4 st0[4], st1[4];
#pragma unroll
            for (int t = 0; t < 4; ++t) {
                st0[t] = mfma16(kf[t], qf0, (f32x4){0.f,0.f,0.f,0.f});
                st1[t] = mfma16(kf[t], qf1, (f32x4){0.f,0.f,0.f,0.f});
            }
            bf16x8 vA0 = *(const bf16x8*)(Vh + (size_t)l16 * 2048 + kv0 + quad * 8);
            bf16x8 vA1 = *(const bf16x8*)(Vh + (size_t)l16 * 2048 + kv0 + 32 + quad * 8);
            bf16x8 vB0 = *(const bf16x8*)(Vh + (size_t)(16 + l16) * 2048 + kv0 + quad * 8);
            bf16x8 vB1 = *(const bf16x8*)(Vh + (size_t)(16 + l16) * 2048 + kv0 + 32 + quad * 8);

            const int qk0 = q0 + l16 - kv0;
            auto softmax_pack = [&](bool masked) {
#pragma unroll
                for (int t = 0; t < 4; ++t) {
                    float p0[4], p1[4];
#pragma unroll
                    for (int r = 0; r < 4; ++r) {
                        const int kk = t * 16 + quad4 + r;
                        float e0 = __expf(st0[t][r]);
                        float e1 = __expf(st1[t][r]);
                        p0[r] = (!masked || kk <= qk0)      ? e0 : 0.f;
                        p1[r] = (!masked || kk <= qk0 + 16) ? e1 : 0.f;
                        rs0 += p0[r]; rs1 += p1[r];
                    }
                    uint2 w0, w1;
                    w0.x = pk2(p0[0], p0[1]); w0.y = pk2(p0[2], p0[3]);
                    w1.x = pk2(p1[0], p1[1]); w1.y = pk2(p1[2], p1[3]);
                    *(uint2*)(P0 + (size_t)l16 * 72 + t * 16 + quad4) = w0;
                    *(uint2*)(P0 + (size_t)(16 + l16) * 72 + t * 16 + quad4) = w1;
                }
            };
            if (kv0 + 63 <= q0) softmax_pack(false); else softmax_pack(true);

            asm volatile("s_waitcnt lgkmcnt(0)" ::: "memory");
#pragma unroll
            for (int ks = 0; ks < 2; ++ks) {
                bf16x8 pa0 = *(const bf16x8*)(P0 + (size_t)l16 * 72 + ks * 32 + quad * 8);
                bf16x8 pa1 = *(const bf16x8*)(P0 + (size_t)(16 + l16) * 72 + ks * 32 + quad * 8);
                bf16x8 va = ks ? vA1 : vA0;
                bf16x8 vb = ks ? vB1 : vB0;
                o00 = mfma16(pa0, va, o00);
                o01 = mfma16(pa0, vb, o01);
                o10 = mfma16(pa1, va, o10);
                o11 = mfma16(pa1, vb, o11);
            }
        }

        rs0 += __shfl_xor(rs0, 16); rs0 += __shfl_xor(rs0, 32);
        rs1 += __shfl_xor(rs1, 16); rs1 += __shfl_xor(rs1, 32);

#pragma unroll
        for (int r = 0; r < 4; ++r) {
            const int qr = q0 + quad4 + r;
            float inv0 = 1.0f / __shfl(rs0, quad4 + r);
            float inv1 = 1.0f / __shfl(rs1, quad4 + r);
            size_t base0 = ((size_t)b * 2048 + qr) * 1024 + h * 32;
            size_t base1 = ((size_t)b * 2048 + qr + 16) * 1024 + h * 32;
            Ctx[base0 + l16]      = f2b(o00[r] * inv0);
            Ctx[base0 + 16 + l16] = f2b(o01[r] * inv0);
            Ctx[base1 + l16]      = f2b(o10[r] * inv1);
            Ctx[base1 + 16 + l16] = f2b(o11[r] * inv1);
        }
    }
}

extern "C" void kernel_launch(void* const* d_in, const int* in_sizes, int n_in,
                              void* d_out, int out_size, void* d_ws, size_t ws_size,
                              hipStream_t stream)
{
    const float* H  = (const float*)d_in[0];
    // d_in[1] = attention_mask (fp32 causal; applied analytically)
    const float* Wq = (const float*)d_in[2];
    const float* bq = (const float*)d_in[3];
    const float* Wk = (const float*)d_in[4];
    const float* bk = (const float*)d_in[5];
    const float* Wv = (const float*)d_in[6];
    const float* bv = (const float*)d_in[7];
    const float* Wo = (const float*)d_in[8];
    const float* bo = (const float*)d_in[9];

    // bf16 workspace (ushort units)
    ushort_t* Hb   = (ushort_t*)d_ws;                   // [4096][2048]  8,388,608
    ushort_t* Wcat = Hb   + (size_t)8388608;            // [3072][2048]  6,291,456
    ushort_t* Qb   = Wcat + (size_t)6291456;            // [64][2048][32] Q
    ushort_t* Kb   = Qb   + (size_t)4194304;            // [64][2048][32] K
    ushort_t* Vtb  = Kb   + (size_t)4194304;            // [64][32][2048] V^T
    ushort_t* Ctx  = Vtb  + (size_t)4194304;            // [4096][1024]  4,194,304
    ushort_t* Wob  = Hb;   // reuse H region after QKV GEMM (stream-serialized)

    dim3 blk(256, 1, 1);
    hipLaunchKernelGGL(cvt_bf16, dim3(4096, 1, 1), blk, 0, stream, H, Hb, 1048576);
    hipLaunchKernelGGL(cvt_w3, dim3(1024, 3, 1), blk, 0, stream, Wq, Wk, Wv, Wcat);

    // fused QKV: 8-phase 128x384, 256 blocks = full fill
    hipLaunchKernelGGL(gemm8c, dim3(32, 8, 1), dim3(512, 1, 1), 0, stream,
                       Hb, Wcat, bq, bk, bv, (void*)Qb, 4096, 3072, 2048);

    hipLaunchKernelGGL(cvt_bf16, dim3(1024, 1, 1), blk, 0, stream, Wo, Wob, 262144);

    // causal-balanced attention: 512 blocks, 34 chunks each
    hipLaunchKernelGGL(attn, dim3(64, 8, 1), blk, 0, stream, Qb, Kb, Vtb, Ctx);

    // Final projection: 8-phase 128x256, 256 blocks = full fill, OUTPUT fp32
    hipLaunchKernelGGL(gemm8b, dim3(32, 8, 1), dim3(512, 1, 1), 0, stream,
                       Ctx, Wob, bo, (float*)d_out, 4096, 2048, 1024, 1.0f);
}

// Round 11
// 274.648 us; speedup vs baseline: 1.0077x; 1.0077x over previous
//
#include <hip/hip_runtime.h>
#include <stdint.h>

typedef __attribute__((ext_vector_type(8))) short bf16x8;
typedef __attribute__((ext_vector_type(4))) float f32x4;
typedef unsigned short ushort_t;

#define AS1 __attribute__((address_space(1)))
#define AS3 __attribute__((address_space(3)))

static __device__ __forceinline__ ushort_t f2b(float f) {
    union { float f; unsigned u; } x; x.f = f;
    unsigned r = x.u + 0x7fffu + ((x.u >> 16) & 1u);  // RNE bf16
    return (ushort_t)(r >> 16);
}
static __device__ __forceinline__ f32x4 mfma16(bf16x8 a, bf16x8 b, f32x4 c) {
    return __builtin_amdgcn_mfma_f32_16x16x32_bf16(a, b, c, 0, 0, 0);
}
static __device__ __forceinline__ void gl_lds16(const ushort_t* g, ushort_t* l) {
    __builtin_amdgcn_global_load_lds((const AS1 void*)g, (AS3 void*)l, 16, 0, 0);
}
// packed fp32x2 -> bf16x2 (RNE), lo = a, hi = b
static __device__ __forceinline__ unsigned pk2(float a, float b) {
    unsigned r;
    asm("v_cvt_pk_bf16_f32 %0, %1, %2" : "=v"(r) : "v"(a), "v"(b));
    return r;
}

// fp32 -> bf16 RNE, 8 elems/thread.
__global__ __launch_bounds__(256)
void cvt_bf16(const float* __restrict__ s, ushort_t* __restrict__ d, int n8)
{
    int i = blockIdx.x * 256 + threadIdx.x;
    if (i >= n8) return;
    const float* p = s + (size_t)i * 8;
    f32x4 a = *(const f32x4*)p;
    f32x4 b = *(const f32x4*)(p + 4);
    bf16x8 r;
#pragma unroll
    for (int j = 0; j < 4; ++j) { r[j] = (short)f2b(a[j]); r[j+4] = (short)f2b(b[j]); }
    *(bf16x8*)(d + (size_t)i * 8) = r;
}

// 3 weight matrices (each 1024x2048 fp32) -> concatenated bf16 [3072][2048].
__global__ __launch_bounds__(256)
void cvt_w3(const float* __restrict__ wq, const float* __restrict__ wk,
            const float* __restrict__ wv, ushort_t* __restrict__ d)
{
    const float* s = (blockIdx.y == 0) ? wq : (blockIdx.y == 1) ? wk : wv;
    ushort_t* dst = d + (size_t)blockIdx.y * 2097152;
    int i = blockIdx.x * 256 + threadIdx.x;          // grid.x = 1024 -> i < 262144
    const float* p = s + (size_t)i * 8;
    f32x4 a = *(const f32x4*)p;
    f32x4 b = *(const f32x4*)(p + 4);
    bf16x8 r;
#pragma unroll
    for (int j = 0; j < 4; ++j) { r[j] = (short)f2b(a[j]); r[j+4] = (short)f2b(b[j]); }
    *(bf16x8*)(dst + (size_t)i * 8) = r;
}

// 128x384 NT-GEMM for the fused QKV, round-10: MERGED 4-phase loop.
// Grid (32, 8) = 256 blocks = full fill. 8 waves (2M x 4N), per-wave C =
// 64x96 (acc[4][6]). Ring: 4 slice-pairs x {B 24KB, A 8KB} = 128KB.
// Each merged phase P: read ALL 10 frags of pair P (slots {2P,2P+1}),
// issue BOTH replacement stages (slots {2P-2,2P-1}, last read one barrier
// ago -> WAR safe), one barrier, one lgkm drain, 24-MFMA burst, counted
// vmcnt(8) (next phase needs stages <= 8t+2P+3; newest 4 stages = 3+1+3+1
// = 8 ops outstanding), one barrier. Halves barrier count vs 8-phase
// (16 -> 8 per K-tile) -- tests the sync-overhead hypothesis after r9's
// lgkm-removal was neutral. vmcnt(0) once at last-tile P==0.
// st_16x32 swizzle both-sides. epi routing: mat=col>>10 (0:Q 1:K 2:V);
// V TRANSPOSED [(b*32+h)][d][s].
__global__ __launch_bounds__(512, 1)
void gemm8c(const ushort_t* __restrict__ A, const ushort_t* __restrict__ B,
            const float* __restrict__ b0, const float* __restrict__ b1,
            const float* __restrict__ b2, void* __restrict__ Cv,
            int M, int N, int K)
{
    __shared__ __align__(16) ushort_t lds[65536];   // 4 x (24KB B + 8KB A) = 128KB
    const int tid = threadIdx.x;
    const int wave = tid >> 6, lane = tid & 63;
    const int l16 = lane & 15, quad = lane >> 4;
    const int wr = wave >> 2, wc = wave & 3;        // 2 x 4 wave grid
    const int bm = blockIdx.x * 128, bn = blockIdx.y * 384;
    const int xo = (l16 & 8) << 1;                  // st_16x32 read XOR (ushorts)
    const int S = K >> 4;                           // stages (2 per 32-k slice)
    const int NT = K >> 7;                          // iterations (128 K each)

    f32x4 acc[4][6];
#pragma unroll
    for (int i = 0; i < 4; ++i)
#pragma unroll
        for (int j = 0; j < 6; ++j) acc[i][j] = (f32x4){0.f,0.f,0.f,0.f};

    // stage s: slot = s&7, pair sp = slot>>1, base = sp*16384 ushorts;
    // even s = B k-slice s/2 (24KB, 3 ops), odd s = A k-slice (8KB, 1 op).
    auto stg = [&](int s_) {
        int slot = s_ & 7;
        ushort_t* base = lds + (slot >> 1) * 16384;
        int ko = (s_ >> 1) << 5;
        if (s_ & 1) {
            int c = tid;
            int cl = c ^ (((c >> 5) & 1) << 1);
            gl_lds16(A + (size_t)(bm + (cl >> 2)) * K + ko + (cl & 3) * 8,
                     base + 12288 + c * 8);
        } else {
#pragma unroll
            for (int call = 0; call < 3; ++call) {
                int c = call * 512 + tid;
                int cl = c ^ (((c >> 5) & 1) << 1);
                gl_lds16(B + (size_t)(bn + (cl >> 2)) * K + ko + (cl & 3) * 8,
                         base + c * 8);
            }
        }
    };

    // prologue: stages 0..5 (12 ops); vmcnt(8) -> stages 0,1 (slots 0,1) landed
#pragma unroll
    for (int s0 = 0; s0 < 6; ++s0) stg(s0);
    asm volatile("s_waitcnt vmcnt(8)" ::: "memory");
    __builtin_amdgcn_s_barrier();

    for (int t = 0; t < NT; ++t) {
        const bool lastit = (t == NT - 1);
        bf16x8 bfr[6], af[4];
#pragma unroll
        for (int P = 0; P < 4; ++P) {
            asm volatile("" ::: "memory");          // pin phase boundary
            const int offB = P * 16384;
            const int offA = offB + 12288;
#pragma unroll
            for (int j = 0; j < 6; ++j)
                bfr[j] = *(const bf16x8*)(lds + offB
                          + (wc * 96 + j * 16 + l16) * 32 + ((quad * 8) ^ xo));
#pragma unroll
            for (int m = 0; m < 4; ++m)
                af[m] = *(const bf16x8*)(lds + offA
                          + (wr * 64 + m * 16 + l16) * 32 + ((quad * 8) ^ xo));
            {   // replacement stages for slots {2P-2, 2P-1} (mod 8)
                int s1 = 8 * t + 6 + 2 * P;
                if (s1 < S) stg(s1);
                int s2 = s1 + 1;
                if (s2 < S) stg(s2);
            }
            __builtin_amdgcn_s_barrier();
            asm volatile("s_waitcnt lgkmcnt(0)" ::: "memory");
            __builtin_amdgcn_sched_barrier(0);      // rule #18: no MFMA hoist
            __builtin_amdgcn_s_setprio(1);
#pragma unroll
            for (int m = 0; m < 4; ++m)
#pragma unroll
                for (int j = 0; j < 6; ++j)
                    acc[m][j] = mfma16(af[m], bfr[j], acc[m][j]);
            __builtin_amdgcn_s_setprio(0);
            if (!lastit)      asm volatile("s_waitcnt vmcnt(8)" ::: "memory");
            else if (P == 0)  asm volatile("s_waitcnt vmcnt(0)" ::: "memory");
            __builtin_amdgcn_s_barrier();
        }
    }

    // epilogue: row = bm + wr*64 + i*16 + quad*4 + r, col = bn + wc*96 + j*16 + l16
#pragma unroll
    for (int i = 0; i < 4; ++i) {
#pragma unroll
        for (int j = 0; j < 6; ++j) {
            int col = bn + wc * 96 + j * 16 + l16;
            int mat = col >> 10, nc = col & 1023;   // uniform across l16 group
            const float* bp = (mat == 0) ? b0 : (mat == 1) ? b1 : b2;
            float bvs = bp[nc];
            int h = nc >> 5, d = nc & 31;
            if (mat == 2) {
                // V^T: [(b*32+h)][d][s], 4 consecutive s packed per lane
                int row0 = bm + wr * 64 + i * 16 + quad * 4;
                int b = row0 >> 11, s2 = row0 & 2047;
                ushort_t* dst = (ushort_t*)Cv + (size_t)2 * 4194304
                              + ((size_t)(b * 32 + h) * 32 + d) * 2048 + s2;
                uint2 w;
                w.x = ((unsigned)f2b(acc[i][j][1] + bvs) << 16) | f2b(acc[i][j][0] + bvs);
                w.y = ((unsigned)f2b(acc[i][j][3] + bvs) << 16) | f2b(acc[i][j][2] + bvs);
                *(uint2*)dst = w;
            } else {
                float sc = (mat == 0) ? 0.125f : 1.0f;
                ushort_t* dst = (ushort_t*)Cv + (size_t)mat * 4194304;
#pragma unroll
                for (int r = 0; r < 4; ++r) {
                    int row = bm + wr * 64 + i * 16 + quad * 4 + r;
                    int b = row >> 11, s2 = row & 2047;
                    float v = (acc[i][j][r] + bvs) * sc;
                    dst[(((size_t)(b * 32 + h) * 2048 + s2) << 5) + d] = f2b(v);
                }
            }
        }
    }
}

// 128x256 8-phase NT-GEMM for the output projection: grid (32, 8) = 256
// blocks -> FULL machine fill. 8 waves (2M x 4N), per-wave C = 64x64.
// Ring: 8 regions, even = B-slice 16KB (2 stage calls), odd = A-slice 8KB
// (1 call) -> 96KB. vmcnt(5) at p==3/7; vmcnt(0) drain at last iteration.
// st_16x32 swizzle both-sides.
__global__ __launch_bounds__(512, 1)
void gemm8b(const ushort_t* __restrict__ A, const ushort_t* __restrict__ B,
            const float* __restrict__ bias, float* __restrict__ C,
            int M, int N, int K, float scale)
{
    __shared__ __align__(16) ushort_t lds[49152];   // 96KB
    const int tid = threadIdx.x;
    const int wave = tid >> 6, lane = tid & 63;
    const int l16 = lane & 15, quad = lane >> 4;
    const int wr = wave >> 2, wc = wave & 3;        // 2 x 4 wave grid
    const int bm = blockIdx.x * 128, bn = blockIdx.y * 256;
    const int xo = (l16 & 8) << 1;                  // st_16x32 read XOR (ushorts)
    const int S = K >> 4;                           // 2 stages per 32-k slice
    const int NT = K >> 7;                          // iterations (128 K each)

    f32x4 acc[4][4];
#pragma unroll
    for (int i = 0; i < 4; ++i)
#pragma unroll
        for (int j = 0; j < 4; ++j) acc[i][j] = (f32x4){0.f,0.f,0.f,0.f};

    // stage s: region r = s&7 at ushort offset (r>>1)*12288 + (r&1)*8192;
    // even s = B k-slice s/2 (16KB, 2 calls), odd s = A k-slice (8KB, 1 call).
    auto stg = [&](int s_) {
        int r = s_ & 7;
        ushort_t* ldst = lds + (r >> 1) * 12288 + (r & 1) * 8192;
        int ko = (s_ >> 1) << 5;
        if (s_ & 1) {
            int c = tid;
            int cl = c ^ (((c >> 5) & 1) << 1);
            gl_lds16(A + (size_t)(bm + (cl >> 2)) * K + ko + (cl & 3) * 8,
                     ldst + c * 8);
        } else {
#pragma unroll
            for (int call = 0; call < 2; ++call) {
                int c = call * 512 + tid;
                int cl = c ^ (((c >> 5) & 1) << 1);
                gl_lds16(B + (size_t)(bn + (cl >> 2)) * K + ko + (cl & 3) * 8,
                         ldst + c * 8);
            }
        }
    };

    // prologue: 7 stages (11 ops); vmcnt(5) -> stages 0-3 landed (phases 0-3)
#pragma unroll
    for (int s0 = 0; s0 < 7; ++s0) stg(s0);
    asm volatile("s_waitcnt vmcnt(5)" ::: "memory");
    __builtin_amdgcn_s_barrier();

    for (int t = 0; t < NT; ++t) {
        const bool lastit = (t == NT - 1);
        bf16x8 bfr[4], af[2];
#pragma unroll
        for (int p = 0; p < 8; ++p) {
            asm volatile("" ::: "memory");
            const int offB = (p >> 1) * 12288;
            const int offA = offB + 8192;
            if ((p & 1) == 0) {                     // new k-slice: read B once
#pragma unroll
                for (int j = 0; j < 4; ++j)
                    bfr[j] = *(const bf16x8*)(lds + offB
                              + (wc * 64 + j * 16 + l16) * 32 + ((quad * 8) ^ xo));
            }
#pragma unroll
            for (int m = 0; m < 2; ++m)
                af[m] = *(const bf16x8*)(lds + offA
                          + (wr * 64 + (p & 1) * 32 + m * 16 + l16) * 32
                          + ((quad * 8) ^ xo));
            { int s_ = 8 * t + 7 + p; if (s_ < S) stg(s_); }
            __builtin_amdgcn_s_barrier();
            asm volatile("s_waitcnt lgkmcnt(0)" ::: "memory");
            __builtin_amdgcn_sched_barrier(0);      // rule #18: no MFMA hoist
            __builtin_amdgcn_s_setprio(1);
#pragma unroll
            for (int m = 0; m < 2; ++m)
#pragma unroll
                for (int j = 0; j < 4; ++j)
                    acc[(p & 1) * 2 + m][j] =
                        mfma16(af[m], bfr[j], acc[(p & 1) * 2 + m][j]);
            __builtin_amdgcn_s_setprio(0);
            if (p == 3) {
                if (lastit) asm volatile("s_waitcnt vmcnt(0)" ::: "memory");
                else        asm volatile("s_waitcnt vmcnt(5)" ::: "memory");
            } else if (p == 7) {
                if (!lastit) asm volatile("s_waitcnt vmcnt(5)" ::: "memory");
            }
            __builtin_amdgcn_s_barrier();
        }
    }

    // epilogue: row = bm + wr*64 + i*16 + quad*4 + r, col = bn + wc*64 + j*16 + l16
#pragma unroll
    for (int i = 0; i < 4; ++i) {
#pragma unroll
        for (int j = 0; j < 4; ++j) {
            int col = bn + wc * 64 + j * 16 + l16;
            float bvs = bias[col];
#pragma unroll
            for (int r = 0; r < 4; ++r) {
                int row = bm + wr * 64 + i * 16 + quad * 4 + r;
                C[(size_t)row * N + col] = (acc[i][j][r] + bvs) * scale;
            }
        }
    }
}

// Flash-style causal attention, barrier-free, CAUSAL-BALANCED: each block
// processes the strip pair (qt, 15-qt) -> constant 34 chunks/block.
// Grid (64 bh, 8 pairs), 256 threads. Swapped QK^T (mfma(K,Q)) puts q on
// l16 so P lands in the PV A-fragment layout; Ps round-trip = 8x
// ds_write_b64 (cvt_pk) + 4x ds_read_b128. K and V^T straight from global.
__global__ __launch_bounds__(256, 4)
void attn(const ushort_t* __restrict__ Q, const ushort_t* __restrict__ Kg,
          const ushort_t* __restrict__ VT, ushort_t* __restrict__ Ctx)
{
    __shared__ __align__(16) ushort_t Ps[4][32 * 72];  // per-wave, padded rows
    const int tid = threadIdx.x, wave = tid >> 6, lane = tid & 63;
    const int l16 = lane & 15, quad = lane >> 4, quad4 = quad * 4;
    const int bh = blockIdx.x;   // 0..63
    const int pr = blockIdx.y;   // 0..7 (strip pair)
    const ushort_t* Qh = Q  + (size_t)bh * 2048 * 32;
    const ushort_t* Kh = Kg + (size_t)bh * 2048 * 32;
    const ushort_t* Vh = VT + (size_t)bh * 32 * 2048;
    const int b = bh >> 5, h = bh & 31;
    ushort_t* P0 = &Ps[wave][0];

    for (int half = 0; half < 2; ++half) {
        const int qt = half ? (15 - pr) : pr;
        const int q0 = qt * 128 + wave * 32;   // wave's 32-row strip

        bf16x8 qf0 = *(const bf16x8*)(Qh + (size_t)(q0 + l16) * 32 + quad * 8);
        bf16x8 qf1 = *(const bf16x8*)(Qh + (size_t)(q0 + 16 + l16) * 32 + quad * 8);

        f32x4 o00 = (f32x4){0.f,0.f,0.f,0.f}, o01 = o00, o10 = o00, o11 = o00;
        float rs0 = 0.f, rs1 = 0.f;

        const int nchw = ((q0 + 31) >> 6) + 1;
        for (int c = 0; c < nchw; ++c) {
            const int kv0 = c * 64;
            bf16x8 kf[4];
#pragma unroll
            for (int t = 0; t < 4; ++t)
                kf[t] = *(const bf16x8*)(Kh + (size_t)(kv0 + t * 16 + l16) * 32 + quad * 8);
            f32x4 st0[4], st1[4];
#pragma unroll
            for (int t = 0; t < 4; ++t) {
                st0[t] = mfma16(kf[t], qf0, (f32x4){0.f,0.f,0.f,0.f});
                st1[t] = mfma16(kf[t], qf1, (f32x4){0.f,0.f,0.f,0.f});
            }
            bf16x8 vA0 = *(const bf16x8*)(Vh + (size_t)l16 * 2048 + kv0 + quad * 8);
            bf16x8 vA1 = *(const bf16x8*)(Vh + (size_t)l16 * 2048 + kv0 + 32 + quad * 8);
            bf16x8 vB0 = *(const bf16x8*)(Vh + (size_t)(16 + l16) * 2048 + kv0 + quad * 8);
            bf16x8 vB1 = *(const bf16x8*)(Vh + (size_t)(16 + l16) * 2048 + kv0 + 32 + quad * 8);

            const int qk0 = q0 + l16 - kv0;
            auto softmax_pack = [&](bool masked) {
#pragma unroll
                for (int t = 0; t < 4; ++t) {
                    float p0[4], p1[4];
#pragma unroll
                    for (int r = 0; r < 4; ++r) {
                        const int kk = t * 16 + quad4 + r;
                        float e0 = __expf(st0[t][r]);
                        float e1 = __expf(st1[t][r]);
                        p0[r] = (!masked || kk <= qk0)      ? e0 : 0.f;
                        p1[r] = (!masked || kk <= qk0 + 16) ? e1 : 0.f;
                        rs0 += p0[r]; rs1 += p1[r];
                    }
                    uint2 w0, w1;
                    w0.x = pk2(p0[0], p0[1]); w0.y = pk2(p0[2], p0[3]);
                    w1.x = pk2(p1[0], p1[1]); w1.y = pk2(p1[2], p1[3]);
                    *(uint2*)(P0 + (size_t)l16 * 72 + t * 16 + quad4) = w0;
                    *(uint2*)(P0 + (size_t)(16 + l16) * 72 + t * 16 + quad4) = w1;
                }
            };
            if (kv0 + 63 <= q0) softmax_pack(false); else softmax_pack(true);

            asm volatile("s_waitcnt lgkmcnt(0)" ::: "memory");
#pragma unroll
            for (int ks = 0; ks < 2; ++ks) {
                bf16x8 pa0 = *(const bf16x8*)(P0 + (size_t)l16 * 72 + ks * 32 + quad * 8);
                bf16x8 pa1 = *(const bf16x8*)(P0 + (size_t)(16 + l16) * 72 + ks * 32 + quad * 8);
                bf16x8 va = ks ? vA1 : vA0;
                bf16x8 vb = ks ? vB1 : vB0;
                o00 = mfma16(pa0, va, o00);
                o01 = mfma16(pa0, vb, o01);
                o10 = mfma16(pa1, va, o10);
                o11 = mfma16(pa1, vb, o11);
            }
        }

        rs0 += __shfl_xor(rs0, 16); rs0 += __shfl_xor(rs0, 32);
        rs1 += __shfl_xor(rs1, 16); rs1 += __shfl_xor(rs1, 32);

#pragma unroll
        for (int r = 0; r < 4; ++r) {
            const int qr = q0 + quad4 + r;
            float inv0 = 1.0f / __shfl(rs0, quad4 + r);
            float inv1 = 1.0f / __shfl(rs1, quad4 + r);
            size_t base0 = ((size_t)b * 2048 + qr) * 1024 + h * 32;
            size_t base1 = ((size_t)b * 2048 + qr + 16) * 1024 + h * 32;
            Ctx[base0 + l16]      = f2b(o00[r] * inv0);
            Ctx[base0 + 16 + l16] = f2b(o01[r] * inv0);
            Ctx[base1 + l16]      = f2b(o10[r] * inv1);
            Ctx[base1 + 16 + l16] = f2b(o11[r] * inv1);
        }
    }
}

extern "C" void kernel_launch(void* const* d_in, const int* in_sizes, int n_in,
                              void* d_out, int out_size, void* d_ws, size_t ws_size,
                              hipStream_t stream)
{
    const float* H  = (const float*)d_in[0];
    // d_in[1] = attention_mask (fp32 causal; applied analytically)
    const float* Wq = (const float*)d_in[2];
    const float* bq = (const float*)d_in[3];
    const float* Wk = (const float*)d_in[4];
    const float* bk = (const float*)d_in[5];
    const float* Wv = (const float*)d_in[6];
    const float* bv = (const float*)d_in[7];
    const float* Wo = (const float*)d_in[8];
    const float* bo = (const float*)d_in[9];

    // bf16 workspace (ushort units)
    ushort_t* Hb   = (ushort_t*)d_ws;                   // [4096][2048]  8,388,608
    ushort_t* Wcat = Hb   + (size_t)8388608;            // [3072][2048]  6,291,456
    ushort_t* Qb   = Wcat + (size_t)6291456;            // [64][2048][32] Q
    ushort_t* Kb   = Qb   + (size_t)4194304;            // [64][2048][32] K
    ushort_t* Vtb  = Kb   + (size_t)4194304;            // [64][32][2048] V^T
    ushort_t* Ctx  = Vtb  + (size_t)4194304;            // [4096][1024]  4,194,304
    ushort_t* Wob  = Hb;   // reuse H region after QKV GEMM (stream-serialized)

    dim3 blk(256, 1, 1);
    hipLaunchKernelGGL(cvt_bf16, dim3(4096, 1, 1), blk, 0, stream, H, Hb, 1048576);
    hipLaunchKernelGGL(cvt_w3, dim3(1024, 3, 1), blk, 0, stream, Wq, Wk, Wv, Wcat);

    // fused QKV: merged 4-phase 128x384, 256 blocks = full fill
    hipLaunchKernelGGL(gemm8c, dim3(32, 8, 1), dim3(512, 1, 1), 0, stream,
                       Hb, Wcat, bq, bk, bv, (void*)Qb, 4096, 3072, 2048);

    hipLaunchKernelGGL(cvt_bf16, dim3(1024, 1, 1), blk, 0, stream, Wo, Wob, 262144);

    // causal-balanced attention: 512 blocks, 34 chunks each
    hipLaunchKernelGGL(attn, dim3(64, 8, 1), blk, 0, stream, Qb, Kb, Vtb, Ctx);

    // Final projection: 8-phase 128x256, 256 blocks = full fill, OUTPUT fp32
    hipLaunchKernelGGL(gemm8b, dim3(32, 8, 1), dim3(512, 1, 1), 0, stream,
                       Ctx, Wob, bo, (float*)d_out, 4096, 2048, 1024, 1.0f);
}

// Round 12
// 271.849 us; speedup vs baseline: 1.0181x; 1.0103x over previous
//
#include <hip/hip_runtime.h>
#include <stdint.h>

typedef __attribute__((ext_vector_type(8))) short bf16x8;
typedef __attribute__((ext_vector_type(4))) float f32x4;
typedef unsigned short ushort_t;

#define AS1 __attribute__((address_space(1)))
#define AS3 __attribute__((address_space(3)))

static __device__ __forceinline__ ushort_t f2b(float f) {
    union { float f; unsigned u; } x; x.f = f;
    unsigned r = x.u + 0x7fffu + ((x.u >> 16) & 1u);  // RNE bf16
    return (ushort_t)(r >> 16);
}
static __device__ __forceinline__ f32x4 mfma16(bf16x8 a, bf16x8 b, f32x4 c) {
    return __builtin_amdgcn_mfma_f32_16x16x32_bf16(a, b, c, 0, 0, 0);
}
static __device__ __forceinline__ void gl_lds16(const ushort_t* g, ushort_t* l) {
    __builtin_amdgcn_global_load_lds((const AS1 void*)g, (AS3 void*)l, 16, 0, 0);
}
// packed fp32x2 -> bf16x2 (RNE), lo = a, hi = b
static __device__ __forceinline__ unsigned pk2(float a, float b) {
    unsigned r;
    asm("v_cvt_pk_bf16_f32 %0, %1, %2" : "=v"(r) : "v"(a), "v"(b));
    return r;
}

// fp32 -> bf16 RNE, 8 elems/thread.
__global__ __launch_bounds__(256)
void cvt_bf16(const float* __restrict__ s, ushort_t* __restrict__ d, int n8)
{
    int i = blockIdx.x * 256 + threadIdx.x;
    if (i >= n8) return;
    const float* p = s + (size_t)i * 8;
    f32x4 a = *(const f32x4*)p;
    f32x4 b = *(const f32x4*)(p + 4);
    bf16x8 r;
#pragma unroll
    for (int j = 0; j < 4; ++j) { r[j] = (short)f2b(a[j]); r[j+4] = (short)f2b(b[j]); }
    *(bf16x8*)(d + (size_t)i * 8) = r;
}

// 3 weight matrices (each 1024x2048 fp32) -> concatenated bf16 [3072][2048].
__global__ __launch_bounds__(256)
void cvt_w3(const float* __restrict__ wq, const float* __restrict__ wk,
            const float* __restrict__ wv, ushort_t* __restrict__ d)
{
    const float* s = (blockIdx.y == 0) ? wq : (blockIdx.y == 1) ? wk : wv;
    ushort_t* dst = d + (size_t)blockIdx.y * 2097152;
    int i = blockIdx.x * 256 + threadIdx.x;          // grid.x = 1024 -> i < 262144
    const float* p = s + (size_t)i * 8;
    f32x4 a = *(const f32x4*)p;
    f32x4 b = *(const f32x4*)(p + 4);
    bf16x8 r;
#pragma unroll
    for (int j = 0; j < 4; ++j) { r[j] = (short)f2b(a[j]); r[j+4] = (short)f2b(b[j]); }
    *(bf16x8*)(dst + (size_t)i * 8) = r;
}

// 128x384 NT-GEMM for the fused QKV, round-12: REG-DOUBLE-BUFFERED frags.
// r11 cycle model: reads (~960cy) serialized with MFMA (~930cy) inside each
// phase = the 2x gap. Fix: phase P issues ds_reads for pair P+1 into the
// ALTERNATE reg set, then MFMAs pair P from resident regs (no wait), then
// lgkmcnt(0) (reads had the whole MFMA burst to complete), vmcnt, ONE
// barrier. Sync proof: pair X read at phase X-1, drained by its closing
// lgkm+barrier, overwritten at X+1 (disjoint from the pair X+3 staged in
// X-1) -> WAR ok; pair P+1 staged at P-2, its 4 ops are >=9-newest at end
// of P-1 -> vmcnt(4) drains -> visible after barrier. lastit: stages cease
// after P=0 -> vmcnt(0) each phase; P=3 read-ahead is dead but harmless.
// Grid (32,8)=256 blocks = full fill; ring 4 pairs x {B 24KB, A 8KB}=128KB;
// st_16x32 swizzle both-sides. epi: mat=col>>10; V TRANSPOSED.
__global__ __launch_bounds__(512, 1)
void gemm8c(const ushort_t* __restrict__ A, const ushort_t* __restrict__ B,
            const float* __restrict__ b0, const float* __restrict__ b1,
            const float* __restrict__ b2, void* __restrict__ Cv,
            int M, int N, int K)
{
    __shared__ __align__(16) ushort_t lds[65536];   // 4 x (24KB B + 8KB A) = 128KB
    const int tid = threadIdx.x;
    const int wave = tid >> 6, lane = tid & 63;
    const int l16 = lane & 15, quad = lane >> 4;
    const int wr = wave >> 2, wc = wave & 3;        // 2 x 4 wave grid
    const int bm = blockIdx.x * 128, bn = blockIdx.y * 384;
    const int xo = (l16 & 8) << 1;                  // st_16x32 read XOR (ushorts)
    const int S = K >> 4;                           // stages (2 per 32-k slice)
    const int NT = K >> 7;                          // iterations (128 K each)

    f32x4 acc[4][6];
#pragma unroll
    for (int i = 0; i < 4; ++i)
#pragma unroll
        for (int j = 0; j < 6; ++j) acc[i][j] = (f32x4){0.f,0.f,0.f,0.f};

    // stage s: slot = s&7, pair sp = slot>>1, base = sp*16384 ushorts;
    // even s = B k-slice s/2 (24KB, 3 ops), odd s = A k-slice (8KB, 1 op).
    auto stg = [&](int s_) {
        int slot = s_ & 7;
        ushort_t* base = lds + (slot >> 1) * 16384;
        int ko = (s_ >> 1) << 5;
        if (s_ & 1) {
            int c = tid;
            int cl = c ^ (((c >> 5) & 1) << 1);
            gl_lds16(A + (size_t)(bm + (cl >> 2)) * K + ko + (cl & 3) * 8,
                     base + 12288 + c * 8);
        } else {
#pragma unroll
            for (int call = 0; call < 3; ++call) {
                int c = call * 512 + tid;
                int cl = c ^ (((c >> 5) & 1) << 1);
                gl_lds16(B + (size_t)(bn + (cl >> 2)) * K + ko + (cl & 3) * 8,
                         base + c * 8);
            }
        }
    };
    // fragment reads of pair pp into caller regs
    auto rdB = [&](int pp, int j) {
        return *(const bf16x8*)(lds + pp * 16384
                 + (wc * 96 + j * 16 + l16) * 32 + ((quad * 8) ^ xo));
    };
    auto rdA = [&](int pp, int m) {
        return *(const bf16x8*)(lds + pp * 16384 + 12288
                 + (wr * 64 + m * 16 + l16) * 32 + ((quad * 8) ^ xo));
    };

    // prologue: stages 0..5 (pairs 0,1,2; 12 ops); vmcnt(4) -> pairs 0,1 landed
#pragma unroll
    for (int s0 = 0; s0 < 6; ++s0) stg(s0);
    asm volatile("s_waitcnt vmcnt(4)" ::: "memory");
    __builtin_amdgcn_s_barrier();

    bf16x8 bfr[2][6], af[2][4];
#pragma unroll
    for (int j = 0; j < 6; ++j) bfr[0][j] = rdB(0, j);
#pragma unroll
    for (int m = 0; m < 4; ++m) af[0][m] = rdA(0, m);
    asm volatile("s_waitcnt lgkmcnt(0)" ::: "memory");

    for (int t = 0; t < NT; ++t) {
        const bool lastit = (t == NT - 1);
#pragma unroll
        for (int P = 0; P < 4; ++P) {
            asm volatile("" ::: "memory");          // pin phase boundary
            const int cur = P & 1, nxt = cur ^ 1;
            const int np = (P + 1) & 3;
            // read-ahead pair P+1 into alternate regs (overlaps MFMA below)
#pragma unroll
            for (int j = 0; j < 6; ++j) bfr[nxt][j] = rdB(np, j);
#pragma unroll
            for (int m = 0; m < 4; ++m) af[nxt][m] = rdA(np, m);
            {   // replacement stages for slots {2P-2, 2P-1} (mod 8)
                int s1 = 8 * t + 6 + 2 * P;
                if (s1 < S) stg(s1);
                int s2 = s1 + 1;
                if (s2 < S) stg(s2);
            }
            __builtin_amdgcn_s_setprio(1);
#pragma unroll
            for (int m = 0; m < 4; ++m)
#pragma unroll
                for (int j = 0; j < 6; ++j)
                    acc[m][j] = mfma16(af[cur][m], bfr[cur][j], acc[m][j]);
            __builtin_amdgcn_s_setprio(0);
            // reads drained before barrier (WAR with next phase's stage)
            asm volatile("s_waitcnt lgkmcnt(0)" ::: "memory");
            if (lastit) asm volatile("s_waitcnt vmcnt(0)" ::: "memory");
            else        asm volatile("s_waitcnt vmcnt(4)" ::: "memory");
            __builtin_amdgcn_s_barrier();
        }
    }

    // epilogue: row = bm + wr*64 + i*16 + quad*4 + r, col = bn + wc*96 + j*16 + l16
#pragma unroll
    for (int i = 0; i < 4; ++i) {
#pragma unroll
        for (int j = 0; j < 6; ++j) {
            int col = bn + wc * 96 + j * 16 + l16;
            int mat = col >> 10, nc = col & 1023;   // uniform across l16 group
            const float* bp = (mat == 0) ? b0 : (mat == 1) ? b1 : b2;
            float bvs = bp[nc];
            int h = nc >> 5, d = nc & 31;
            if (mat == 2) {
                // V^T: [(b*32+h)][d][s], 4 consecutive s packed per lane
                int row0 = bm + wr * 64 + i * 16 + quad * 4;
                int b = row0 >> 11, s2 = row0 & 2047;
                ushort_t* dst = (ushort_t*)Cv + (size_t)2 * 4194304
                              + ((size_t)(b * 32 + h) * 32 + d) * 2048 + s2;
                uint2 w;
                w.x = ((unsigned)f2b(acc[i][j][1] + bvs) << 16) | f2b(acc[i][j][0] + bvs);
                w.y = ((unsigned)f2b(acc[i][j][3] + bvs) << 16) | f2b(acc[i][j][2] + bvs);
                *(uint2*)dst = w;
            } else {
                float sc = (mat == 0) ? 0.125f : 1.0f;
                ushort_t* dst = (ushort_t*)Cv + (size_t)mat * 4194304;
#pragma unroll
                for (int r = 0; r < 4; ++r) {
                    int row = bm + wr * 64 + i * 16 + quad * 4 + r;
                    int b = row >> 11, s2 = row & 2047;
                    float v = (acc[i][j][r] + bvs) * sc;
                    dst[(((size_t)(b * 32 + h) * 2048 + s2) << 5) + d] = f2b(v);
                }
            }
        }
    }
}

// 128x256 8-phase NT-GEMM for the output projection: grid (32, 8) = 256
// blocks -> FULL machine fill. 8 waves (2M x 4N), per-wave C = 64x64.
// Ring: 8 regions, even = B-slice 16KB (2 stage calls), odd = A-slice 8KB
// (1 call) -> 96KB. vmcnt(5) at p==3/7; vmcnt(0) drain at last iteration.
// st_16x32 swizzle both-sides.
__global__ __launch_bounds__(512, 1)
void gemm8b(const ushort_t* __restrict__ A, const ushort_t* __restrict__ B,
            const float* __restrict__ bias, float* __restrict__ C,
            int M, int N, int K, float scale)
{
    __shared__ __align__(16) ushort_t lds[49152];   // 96KB
    const int tid = threadIdx.x;
    const int wave = tid >> 6, lane = tid & 63;
    const int l16 = lane & 15, quad = lane >> 4;
    const int wr = wave >> 2, wc = wave & 3;        // 2 x 4 wave grid
    const int bm = blockIdx.x * 128, bn = blockIdx.y * 256;
    const int xo = (l16 & 8) << 1;                  // st_16x32 read XOR (ushorts)
    const int S = K >> 4;                           // 2 stages per 32-k slice
    const int NT = K >> 7;                          // iterations (128 K each)

    f32x4 acc[4][4];
#pragma unroll
    for (int i = 0; i < 4; ++i)
#pragma unroll
        for (int j = 0; j < 4; ++j) acc[i][j] = (f32x4){0.f,0.f,0.f,0.f};

    // stage s: region r = s&7 at ushort offset (r>>1)*12288 + (r&1)*8192;
    // even s = B k-slice s/2 (16KB, 2 calls), odd s = A k-slice (8KB, 1 call).
    auto stg = [&](int s_) {
        int r = s_ & 7;
        ushort_t* ldst = lds + (r >> 1) * 12288 + (r & 1) * 8192;
        int ko = (s_ >> 1) << 5;
        if (s_ & 1) {
            int c = tid;
            int cl = c ^ (((c >> 5) & 1) << 1);
            gl_lds16(A + (size_t)(bm + (cl >> 2)) * K + ko + (cl & 3) * 8,
                     ldst + c * 8);
        } else {
#pragma unroll
            for (int call = 0; call < 2; ++call) {
                int c = call * 512 + tid;
                int cl = c ^ (((c >> 5) & 1) << 1);
                gl_lds16(B + (size_t)(bn + (cl >> 2)) * K + ko + (cl & 3) * 8,
                         ldst + c * 8);
            }
        }
    };

    // prologue: 7 stages (11 ops); vmcnt(5) -> stages 0-3 landed (phases 0-3)
#pragma unroll
    for (int s0 = 0; s0 < 7; ++s0) stg(s0);
    asm volatile("s_waitcnt vmcnt(5)" ::: "memory");
    __builtin_amdgcn_s_barrier();

    for (int t = 0; t < NT; ++t) {
        const bool lastit = (t == NT - 1);
        bf16x8 bfr[4], af[2];
#pragma unroll
        for (int p = 0; p < 8; ++p) {
            asm volatile("" ::: "memory");
            const int offB = (p >> 1) * 12288;
            const int offA = offB + 8192;
            if ((p & 1) == 0) {                     // new k-slice: read B once
#pragma unroll
                for (int j = 0; j < 4; ++j)
                    bfr[j] = *(const bf16x8*)(lds + offB
                              + (wc * 64 + j * 16 + l16) * 32 + ((quad * 8) ^ xo));
            }
#pragma unroll
            for (int m = 0; m < 2; ++m)
                af[m] = *(const bf16x8*)(lds + offA
                          + (wr * 64 + (p & 1) * 32 + m * 16 + l16) * 32
                          + ((quad * 8) ^ xo));
            { int s_ = 8 * t + 7 + p; if (s_ < S) stg(s_); }
            __builtin_amdgcn_s_barrier();
            asm volatile("s_waitcnt lgkmcnt(0)" ::: "memory");
            __builtin_amdgcn_sched_barrier(0);      // rule #18: no MFMA hoist
            __builtin_amdgcn_s_setprio(1);
#pragma unroll
            for (int m = 0; m < 2; ++m)
#pragma unroll
                for (int j = 0; j < 4; ++j)
                    acc[(p & 1) * 2 + m][j] =
                        mfma16(af[m], bfr[j], acc[(p & 1) * 2 + m][j]);
            __builtin_amdgcn_s_setprio(0);
            if (p == 3) {
                if (lastit) asm volatile("s_waitcnt vmcnt(0)" ::: "memory");
                else        asm volatile("s_waitcnt vmcnt(5)" ::: "memory");
            } else if (p == 7) {
                if (!lastit) asm volatile("s_waitcnt vmcnt(5)" ::: "memory");
            }
            __builtin_amdgcn_s_barrier();
        }
    }

    // epilogue: row = bm + wr*64 + i*16 + quad*4 + r, col = bn + wc*64 + j*16 + l16
#pragma unroll
    for (int i = 0; i < 4; ++i) {
#pragma unroll
        for (int j = 0; j < 4; ++j) {
            int col = bn + wc * 64 + j * 16 + l16;
            float bvs = bias[col];
#pragma unroll
            for (int r = 0; r < 4; ++r) {
                int row = bm + wr * 64 + i * 16 + quad * 4 + r;
                C[(size_t)row * N + col] = (acc[i][j][r] + bvs) * scale;
            }
        }
    }
}

// Flash-style causal attention, barrier-free, CAUSAL-BALANCED: each block
// processes the strip pair (qt, 15-qt) -> constant 34 chunks/block.
// Grid (64 bh, 8 pairs), 256 threads. Swapped QK^T (mfma(K,Q)) puts q on
// l16 so P lands in the PV A-fragment layout; Ps round-trip = 8x
// ds_write_b64 (cvt_pk) + 4x ds_read_b128. K and V^T straight from global.
__global__ __launch_bounds__(256, 4)
void attn(const ushort_t* __restrict__ Q, const ushort_t* __restrict__ Kg,
          const ushort_t* __restrict__ VT, ushort_t* __restrict__ Ctx)
{
    __shared__ __align__(16) ushort_t Ps[4][32 * 72];  // per-wave, padded rows
    const int tid = threadIdx.x, wave = tid >> 6, lane = tid & 63;
    const int l16 = lane & 15, quad = lane >> 4, quad4 = quad * 4;
    const int bh = blockIdx.x;   // 0..63
    const int pr = blockIdx.y;   // 0..7 (strip pair)
    const ushort_t* Qh = Q  + (size_t)bh * 2048 * 32;
    const ushort_t* Kh = Kg + (size_t)bh * 2048 * 32;
    const ushort_t* Vh = VT + (size_t)bh * 32 * 2048;
    const int b = bh >> 5, h = bh & 31;
    ushort_t* P0 = &Ps[wave][0];

    for (int half = 0; half < 2; ++half) {
        const int qt = half ? (15 - pr) : pr;
        const int q0 = qt * 128 + wave * 32;   // wave's 32-row strip

        bf16x8 qf0 = *(const bf16x8*)(Qh + (size_t)(q0 + l16) * 32 + quad * 8);
        bf16x8 qf1 = *(const bf16x8*)(Qh + (size_t)(q0 + 16 + l16) * 32 + quad * 8);

        f32x4 o00 = (f32x4){0.f,0.f,0.f,0.f}, o01 = o00, o10 = o00, o11 = o00;
        float rs0 = 0.f, rs1 = 0.f;

        const int nchw = ((q0 + 31) >> 6) + 1;
        for (int c = 0; c < nchw; ++c) {
            const int kv0 = c * 64;
            bf16x8 kf[4];
#pragma unroll
            for (int t = 0; t < 4; ++t)
                kf[t] = *(const bf16x8*)(Kh + (size_t)(kv0 + t * 16 + l16) * 32 + quad * 8);
            f32x4 st0[4], st1[4];
#pragma unroll
            for (int t = 0; t < 4; ++t) {
                st0[t] = mfma16(kf[t], qf0, (f32x4){0.f,0.f,0.f,0.f});
                st1[t] = mfma16(kf[t], qf1, (f32x4){0.f,0.f,0.f,0.f});
            }
            bf16x8 vA0 = *(const bf16x8*)(Vh + (size_t)l16 * 2048 + kv0 + quad * 8);
            bf16x8 vA1 = *(const bf16x8*)(Vh + (size_t)l16 * 2048 + kv0 + 32 + quad * 8);
            bf16x8 vB0 = *(const bf16x8*)(Vh + (size_t)(16 + l16) * 2048 + kv0 + quad * 8);
            bf16x8 vB1 = *(const bf16x8*)(Vh + (size_t)(16 + l16) * 2048 + kv0 + 32 + quad * 8);

            const int qk0 = q0 + l16 - kv0;
            auto softmax_pack = [&](bool masked) {
#pragma unroll
                for (int t = 0; t < 4; ++t) {
                    float p0[4], p1[4];
#pragma unroll
                    for (int r = 0; r < 4; ++r) {
                        const int kk = t * 16 + quad4 + r;
                        float e0 = __expf(st0[t][r]);
                        float e1 = __expf(st1[t][r]);
                        p0[r] = (!masked || kk <= qk0)      ? e0 : 0.f;
                        p1[r] = (!masked || kk <= qk0 + 16) ? e1 : 0.f;
                        rs0 += p0[r]; rs1 += p1[r];
                    }
                    uint2 w0, w1;
                    w0.x = pk2(p0[0], p0[1]); w0.y = pk2(p0[2], p0[3]);
                    w1.x = pk2(p1[0], p1[1]); w1.y = pk2(p1[2], p1[3]);
                    *(uint2*)(P0 + (size_t)l16 * 72 + t * 16 + quad4) = w0;
                    *(uint2*)(P0 + (size_t)(16 + l16) * 72 + t * 16 + quad4) = w1;
                }
            };
            if (kv0 + 63 <= q0) softmax_pack(false); else softmax_pack(true);

            asm volatile("s_waitcnt lgkmcnt(0)" ::: "memory");
#pragma unroll
            for (int ks = 0; ks < 2; ++ks) {
                bf16x8 pa0 = *(const bf16x8*)(P0 + (size_t)l16 * 72 + ks * 32 + quad * 8);
                bf16x8 pa1 = *(const bf16x8*)(P0 + (size_t)(16 + l16) * 72 + ks * 32 + quad * 8);
                bf16x8 va = ks ? vA1 : vA0;
                bf16x8 vb = ks ? vB1 : vB0;
                o00 = mfma16(pa0, va, o00);
                o01 = mfma16(pa0, vb, o01);
                o10 = mfma16(pa1, va, o10);
                o11 = mfma16(pa1, vb, o11);
            }
        }

        rs0 += __shfl_xor(rs0, 16); rs0 += __shfl_xor(rs0, 32);
        rs1 += __shfl_xor(rs1, 16); rs1 += __shfl_xor(rs1, 32);

#pragma unroll
        for (int r = 0; r < 4; ++r) {
            const int qr = q0 + quad4 + r;
            float inv0 = 1.0f / __shfl(rs0, quad4 + r);
            float inv1 = 1.0f / __shfl(rs1, quad4 + r);
            size_t base0 = ((size_t)b * 2048 + qr) * 1024 + h * 32;
            size_t base1 = ((size_t)b * 2048 + qr + 16) * 1024 + h * 32;
            Ctx[base0 + l16]      = f2b(o00[r] * inv0);
            Ctx[base0 + 16 + l16] = f2b(o01[r] * inv0);
            Ctx[base1 + l16]      = f2b(o10[r] * inv1);
            Ctx[base1 + 16 + l16] = f2b(o11[r] * inv1);
        }
    }
}

extern "C" void kernel_launch(void* const* d_in, const int* in_sizes, int n_in,
                              void* d_out, int out_size, void* d_ws, size_t ws_size,
                              hipStream_t stream)
{
    const float* H  = (const float*)d_in[0];
    // d_in[1] = attention_mask (fp32 causal; applied analytically)
    const float* Wq = (const float*)d_in[2];
    const float* bq = (const float*)d_in[3];
    const float* Wk = (const float*)d_in[4];
    const float* bk = (const float*)d_in[5];
    const float* Wv = (const float*)d_in[6];
    const float* bv = (const float*)d_in[7];
    const float* Wo = (const float*)d_in[8];
    const float* bo = (const float*)d_in[9];

    // bf16 workspace (ushort units)
    ushort_t* Hb   = (ushort_t*)d_ws;                   // [4096][2048]  8,388,608
    ushort_t* Wcat = Hb   + (size_t)8388608;            // [3072][2048]  6,291,456
    ushort_t* Qb   = Wcat + (size_t)6291456;            // [64][2048][32] Q
    ushort_t* Kb   = Qb   + (size_t)4194304;            // [64][2048][32] K
    ushort_t* Vtb  = Kb   + (size_t)4194304;            // [64][32][2048] V^T
    ushort_t* Ctx  = Vtb  + (size_t)4194304;            // [4096][1024]  4,194,304
    ushort_t* Wob  = Hb;   // reuse H region after QKV GEMM (stream-serialized)

    dim3 blk(256, 1, 1);
    hipLaunchKernelGGL(cvt_bf16, dim3(4096, 1, 1), blk, 0, stream, H, Hb, 1048576);
    hipLaunchKernelGGL(cvt_w3, dim3(1024, 3, 1), blk, 0, stream, Wq, Wk, Wv, Wcat);

    // fused QKV: reg-double-buffered 4-phase 128x384, 256 blocks = full fill
    hipLaunchKernelGGL(gemm8c, dim3(32, 8, 1), dim3(512, 1, 1), 0, stream,
                       Hb, Wcat, bq, bk, bv, (void*)Qb, 4096, 3072, 2048);

    hipLaunchKernelGGL(cvt_bf16, dim3(1024, 1, 1), blk, 0, stream, Wo, Wob, 262144);

    // causal-balanced attention: 512 blocks, 34 chunks each
    hipLaunchKernelGGL(attn, dim3(64, 8, 1), blk, 0, stream, Qb, Kb, Vtb, Ctx);

    // Final projection: 8-phase 128x256, 256 blocks = full fill, OUTPUT fp32
    hipLaunchKernelGGL(gemm8b, dim3(32, 8, 1), dim3(512, 1, 1), 0, stream,
                       Ctx, Wob, bo, (float*)d_out, 4096, 2048, 1024, 1.0f);
}